// Round 1
// baseline (585.883 us; speedup 1.0000x reference)
//
#include <hip/hip_runtime.h>
#include <hip/hip_bf16.h>
#include <math.h>

// Problem constants
#define B   64
#define C   1024
#define HH  16
#define DD  64
#define MM  2048
#define LL  2049   // M+1
#define NCH 8
#define SCALE 0.125f

// ---------------- K0: q = x@Wq + bq ; qu = q+u ; qv = q+v ----------------
// grid (16, 4): j0 = bx*64, b0 = by*16 ; block 256
__global__ __launch_bounds__(256) void k_qproj(
    const float* __restrict__ x, const float* __restrict__ Wq,
    const float* __restrict__ bq, const float* __restrict__ u_bias,
    const float* __restrict__ v_bias, float* __restrict__ qu,
    float* __restrict__ qv) {
  __shared__ __attribute__((aligned(16))) float xs[16 * 1024];
  int t = threadIdx.x;
  int j0 = blockIdx.x * 64, b0 = blockIdx.y * 16;
  for (int i4 = t; i4 < 16 * 256; i4 += 256) {
    int row = i4 >> 8, c4 = i4 & 255;
    *(float4*)&xs[row * 1024 + 4 * c4] =
        *(const float4*)&x[(size_t)(b0 + row) * 1024 + 4 * c4];
  }
  __syncthreads();
  int d = t & 63, w = t >> 6;
  int j = j0 + d;
  float a0 = 0, a1 = 0, a2 = 0, a3 = 0;
  for (int c = 0; c < 1024; ++c) {
    float wv = Wq[(size_t)c * 1024 + j];
    a0 += xs[(w + 0) * 1024 + c] * wv;
    a1 += xs[(w + 4) * 1024 + c] * wv;
    a2 += xs[(w + 8) * 1024 + c] * wv;
    a3 += xs[(w + 12) * 1024 + c] * wv;
  }
  float qb = bq[j], uf = u_bias[j], vf = v_bias[j];
  float q0 = a0 + qb, q1 = a1 + qb, q2 = a2 + qb, q3 = a3 + qb;
  qu[(size_t)(b0 + w) * 1024 + j] = q0 + uf;
  qv[(size_t)(b0 + w) * 1024 + j] = q0 + vf;
  qu[(size_t)(b0 + w + 4) * 1024 + j] = q1 + uf;
  qv[(size_t)(b0 + w + 4) * 1024 + j] = q1 + vf;
  qu[(size_t)(b0 + w + 8) * 1024 + j] = q2 + uf;
  qv[(size_t)(b0 + w + 8) * 1024 + j] = q2 + vf;
  qu[(size_t)(b0 + w + 12) * 1024 + j] = q3 + uf;
  qv[(size_t)(b0 + w + 12) * 1024 + j] = q3 + vf;
}

// ---------------- K1: wt[b,h,c] = sum_d qu[b,h,d] * Wk[c, h*64+d] ----------------
// grid (16, 64): h = bx, b = by ; block 256
__global__ __launch_bounds__(256) void k_wtilde(
    const float* __restrict__ qu, const float* __restrict__ Wk,
    float* __restrict__ wt) {
  __shared__ float qs[64];
  int t = threadIdx.x, h = blockIdx.x, b = blockIdx.y;
  if (t < 64) qs[t] = qu[(size_t)b * 1024 + h * 64 + t];
  __syncthreads();
  for (int c = t; c < 1024; c += 256) {
    const float* wr = &Wk[(size_t)c * 1024 + h * 64];
    float s = 0.f;
#pragma unroll
    for (int d4 = 0; d4 < 16; ++d4) {
      float4 wv = *(const float4*)&wr[4 * d4];
      s += wv.x * qs[4 * d4 + 0] + wv.y * qs[4 * d4 + 1] +
           wv.z * qs[4 * d4 + 2] + wv.w * qs[4 * d4 + 3];
    }
    wt[(size_t)(b * 16 + h) * 1024 + c] = s;
  }
}

// ---------------- K2: sinusoidal table, reversed: rtab[l*64+d] ----------------
__global__ void k_rtab(float* __restrict__ rtab) {
  int idx = blockIdx.x * 256 + threadIdx.x;
  if (idx >= LL * 64) return;
  int l = idx >> 6, d = idx & 63;
  float p = (float)(LL - 1 - l);
  int dd = d & 31;
  float f = 1.0f / powf(10000.0f, (float)dd * (1.0f / 32.0f));
  float a = p * f;
  rtab[idx] = (d < 32) ? sinf(a) : cosf(a);
}

// ---------------- K3: logits[b,h,l] = (cat[b,l,:].wt[b,h,:] + qv[b,h,:].r[l,:]) * scale
// grid (16, 64): ch = bx (129 rows each), b = by ; block 256 = 4 waves.
// wave w handles h in {4w..4w+3}; lane = cg*4+hl: hl->h, cg->64-elem c-slice.
#define K3_NR 8
__global__ __launch_bounds__(256) void k_logits(
    const float* __restrict__ x, const float* __restrict__ mem,
    const float* __restrict__ wt, const float* __restrict__ qv,
    const float* __restrict__ rtab, float* __restrict__ logits) {
  __shared__ __attribute__((aligned(16))) float cat_s[K3_NR * 1088];  // 16 chunks of 68 per row
  __shared__ __attribute__((aligned(16))) float r_s[K3_NR * 68];
  int t = threadIdx.x;
  int lane = t & 63, w = t >> 6;
  int cg = lane >> 2, hl = lane & 3;
  int b = blockIdx.y, ch = blockIdx.x;
  int l0b = ch * 129, lend = min(LL, l0b + 129);
  int h = w * 4 + hl;
  float4 wreg[16];
  const float* wbase = &wt[(size_t)(b * 16 + h) * 1024 + cg * 64];
#pragma unroll
  for (int i = 0; i < 16; ++i) wreg[i] = *(const float4*)&wbase[4 * i];
  float4 qvr = *(const float4*)&qv[(size_t)b * 1024 + h * 64 + 4 * cg];

  for (int g0 = l0b; g0 < lend; g0 += K3_NR) {
    int nr = min(K3_NR, lend - g0);
    // stage cat rows (padded 68-chunks) and r rows
    for (int i = t; i < nr * 256; i += 256) {
      int row = i >> 8, c4 = i & 255;
      int l = g0 + row;
      const float* src = (l < MM) ? &mem[((size_t)b * MM + l) * 1024]
                                  : &x[(size_t)b * 1024];
      float4 v = *(const float4*)&src[4 * c4];
      int chunk = c4 >> 4, off = (c4 & 15) * 4;
      *(float4*)&cat_s[row * 1088 + chunk * 68 + off] = v;
    }
    for (int i = t; i < nr * 16; i += 256) {
      int row = i >> 4, d4 = i & 15;
      *(float4*)&r_s[row * 68 + 4 * d4] =
          *(const float4*)&rtab[(size_t)(g0 + row) * 64 + 4 * d4];
    }
    __syncthreads();
    for (int row = 0; row < nr; ++row) {
      const float* cr = &cat_s[row * 1088 + cg * 68];
      float4 rv = *(const float4*)&r_s[row * 68 + 4 * cg];
      float part = qvr.x * rv.x + qvr.y * rv.y + qvr.z * rv.z + qvr.w * rv.w;
#pragma unroll
      for (int i = 0; i < 16; ++i) {
        float4 cv = *(const float4*)&cr[4 * i];
        part += cv.x * wreg[i].x + cv.y * wreg[i].y + cv.z * wreg[i].z +
                cv.w * wreg[i].w;
      }
      part += __shfl_xor(part, 4, 64);
      part += __shfl_xor(part, 8, 64);
      part += __shfl_xor(part, 16, 64);
      part += __shfl_xor(part, 32, 64);
      if (cg == 0)
        logits[(size_t)(b * 16 + h) * LL + (g0 + row)] = part * SCALE;
    }
    __syncthreads();
  }
}

// ---------------- K4: softmax over l, in place. grid 1024 (b*16+h) ----------------
__global__ __launch_bounds__(256) void k_softmax(float* __restrict__ logits) {
  __shared__ float red[8];
  int t = threadIdx.x;
  size_t base = (size_t)blockIdx.x * LL;
  float rv[9];
  float m = -1e30f;
#pragma unroll
  for (int k = 0; k < 9; ++k) {
    int i = t + k * 256;
    rv[k] = (i < LL) ? logits[base + i] : -1e30f;
    m = fmaxf(m, rv[k]);
  }
#pragma unroll
  for (int s = 1; s < 64; s <<= 1) m = fmaxf(m, __shfl_xor(m, s, 64));
  if ((t & 63) == 0) red[t >> 6] = m;
  __syncthreads();
  m = fmaxf(fmaxf(red[0], red[1]), fmaxf(red[2], red[3]));
  float sum = 0.f;
#pragma unroll
  for (int k = 0; k < 9; ++k) {
    int i = t + k * 256;
    float e = __expf(rv[k] - m);
    rv[k] = e;
    if (i < LL) sum += e;
  }
#pragma unroll
  for (int s = 1; s < 64; s <<= 1) sum += __shfl_xor(sum, s, 64);
  if ((t & 63) == 0) red[4 + (t >> 6)] = sum;
  __syncthreads();
  float inv = 1.0f / (red[4] + red[5] + red[6] + red[7]);
#pragma unroll
  for (int k = 0; k < 9; ++k) {
    int i = t + k * 256;
    if (i < LL) logits[base + i] = rv[k] * inv;
  }
}

// ---------------- K5: partial ctx[b,ch,h,c] = sum_{l in chunk} attn[b,h,l]*cat[b,l,c]
// grid (8, 64): ch = bx, b = by ; block 256, thread owns c = 4t..4t+3 for all 16 h.
__global__ __launch_bounds__(256) void k_ctx(
    const float* __restrict__ x, const float* __restrict__ mem,
    const float* __restrict__ attn, float* __restrict__ part) {
  __shared__ float as[16][256];
  int t = threadIdx.x;
  int b = blockIdx.y, ch = blockIdx.x;
  int lstart = ch * 257, lend = min(LL, lstart + 257);
  float4 a[16];
#pragma unroll
  for (int h = 0; h < 16; ++h) a[h] = make_float4(0.f, 0.f, 0.f, 0.f);
  for (int g0 = lstart; g0 < lend; g0 += 256) {
    int ng = min(256, lend - g0);
    __syncthreads();
#pragma unroll
    for (int h = 0; h < 16; ++h)
      for (int j = t; j < ng; j += 256)
        as[h][j] = attn[(size_t)(b * 16 + h) * LL + g0 + j];
    __syncthreads();
    for (int ll = 0; ll < ng; ++ll) {
      int l = g0 + ll;
      const float* src = (l < MM) ? &mem[((size_t)b * MM + l) * 1024]
                                  : &x[(size_t)b * 1024];
      float4 cv = *(const float4*)&src[4 * t];
#pragma unroll
      for (int h = 0; h < 16; ++h) {
        float p = as[h][ll];
        a[h].x += p * cv.x; a[h].y += p * cv.y;
        a[h].z += p * cv.z; a[h].w += p * cv.w;
      }
    }
  }
#pragma unroll
  for (int h = 0; h < 16; ++h)
    *(float4*)&part[(size_t)((b * 8 + ch) * 16 + h) * 1024 + 4 * t] = a[h];
}

// ---------------- K6: ctx = sum over 8 chunks ----------------
__global__ __launch_bounds__(256) void k_ctxreduce(
    const float* __restrict__ part, float* __restrict__ ctx) {
  int o4 = blockIdx.x * 256 + threadIdx.x;  // 262144 total
  size_t o = (size_t)o4 * 4;
  int b = (int)(o >> 14);
  int rem = (int)(o & 16383);
  const float* p = &part[(size_t)b * 131072 + rem];
  float4 s = *(const float4*)p;
#pragma unroll
  for (int chk = 1; chk < 8; ++chk) {
    float4 v = *(const float4*)&p[(size_t)chk * 16384];
    s.x += v.x; s.y += v.y; s.z += v.z; s.w += v.w;
  }
  *(float4*)&ctx[o] = s;
}

// ---------------- K7: out1[b, h*64+d] = ctx[b,h,:] @ Wv[:, h*64+d] + bv ----------------
// grid (16, 4): h = bx, b0 = by*16 ; block 256
__global__ __launch_bounds__(256) void k_ov(
    const float* __restrict__ ctx, const float* __restrict__ Wv,
    const float* __restrict__ bv, float* __restrict__ out1) {
  __shared__ __attribute__((aligned(16))) float xs[16 * 1024];
  int t = threadIdx.x, h = blockIdx.x, b0 = blockIdx.y * 16;
  for (int i4 = t; i4 < 4096; i4 += 256) {
    int row = i4 >> 8, c4 = i4 & 255;
    *(float4*)&xs[row * 1024 + 4 * c4] =
        *(const float4*)&ctx[(size_t)((b0 + row) * 16 + h) * 1024 + 4 * c4];
  }
  __syncthreads();
  int d = t & 63, w = t >> 6;
  int j = h * 64 + d;
  float a0 = 0, a1 = 0, a2 = 0, a3 = 0;
  for (int c = 0; c < 1024; ++c) {
    float wv = Wv[(size_t)c * 1024 + j];
    a0 += xs[(w + 0) * 1024 + c] * wv;
    a1 += xs[(w + 4) * 1024 + c] * wv;
    a2 += xs[(w + 8) * 1024 + c] * wv;
    a3 += xs[(w + 12) * 1024 + c] * wv;
  }
  float bb = bv[j];
  out1[(size_t)(b0 + w) * 1024 + j] = a0 + bb;
  out1[(size_t)(b0 + w + 4) * 1024 + j] = a1 + bb;
  out1[(size_t)(b0 + w + 8) * 1024 + j] = a2 + bb;
  out1[(size_t)(b0 + w + 12) * 1024 + j] = a3 + bb;
}

// ---------------- K8: dout = out1 @ Wo + bo ----------------
// grid (16, 4): j0 = bx*64, b0 = by*16 ; block 256
__global__ __launch_bounds__(256) void k_out(
    const float* __restrict__ out1, const float* __restrict__ Wo,
    const float* __restrict__ bo, float* __restrict__ dout) {
  __shared__ __attribute__((aligned(16))) float xs[16 * 1024];
  int t = threadIdx.x, j0 = blockIdx.x * 64, b0 = blockIdx.y * 16;
  for (int i4 = t; i4 < 4096; i4 += 256) {
    int row = i4 >> 8, c4 = i4 & 255;
    *(float4*)&xs[row * 1024 + 4 * c4] =
        *(const float4*)&out1[(size_t)(b0 + row) * 1024 + 4 * c4];
  }
  __syncthreads();
  int d = t & 63, w = t >> 6;
  int j = j0 + d;
  float a0 = 0, a1 = 0, a2 = 0, a3 = 0;
  for (int c = 0; c < 1024; ++c) {
    float wv = Wo[(size_t)c * 1024 + j];
    a0 += xs[(w + 0) * 1024 + c] * wv;
    a1 += xs[(w + 4) * 1024 + c] * wv;
    a2 += xs[(w + 8) * 1024 + c] * wv;
    a3 += xs[(w + 12) * 1024 + c] * wv;
  }
  float bb = bo[j];
  dout[(size_t)(b0 + w) * 1024 + j] = a0 + bb;
  dout[(size_t)(b0 + w + 4) * 1024 + j] = a1 + bb;
  dout[(size_t)(b0 + w + 8) * 1024 + j] = a2 + bb;
  dout[(size_t)(b0 + w + 12) * 1024 + j] = a3 + bb;
}

extern "C" void kernel_launch(void* const* d_in, const int* in_sizes, int n_in,
                              void* d_out, int out_size, void* d_ws,
                              size_t ws_size, hipStream_t stream) {
  const float* x = (const float*)d_in[0];
  const float* mem = (const float*)d_in[1];
  const float* Wq = (const float*)d_in[2];
  const float* bq = (const float*)d_in[3];
  const float* Wk = (const float*)d_in[4];
  // d_in[5] = bk : constant over l -> cancels in softmax, unused.
  const float* Wv = (const float*)d_in[6];
  const float* bv = (const float*)d_in[7];
  const float* u_bias = (const float*)d_in[8];
  const float* v_bias = (const float*)d_in[9];
  const float* Wo = (const float*)d_in[10];
  const float* bo = (const float*)d_in[11];
  float* out = (float*)d_out;

  float* ws = (float*)d_ws;
  // ws layout (floats)
  float* qu = ws;                       // 65536
  float* qv = qu + 65536;               // 65536
  float* wt = qv + 65536;               // 1048576
  float* rtab = wt + 1048576;           // 131200 (padded)
  float* logits = rtab + 131200;        // 2098176  (B*H*L)
  float* part = logits + 2098176;       // 8388608  (B*8*H*C)
  float* ctx = part + 8388608;          // 1048576
  float* out1 = ctx + 1048576;          // 65536
  // total = 12,911,744 floats = 51.6 MB

  k_qproj<<<dim3(16, 4), 256, 0, stream>>>(x, Wq, bq, u_bias, v_bias, qu, qv);
  k_rtab<<<dim3((LL * 64 + 255) / 256), 256, 0, stream>>>(rtab);
  k_wtilde<<<dim3(16, 64), 256, 0, stream>>>(qu, Wk, wt);
  k_logits<<<dim3(16, 64), 256, 0, stream>>>(x, mem, wt, qv, rtab, logits);
  k_softmax<<<dim3(1024), 256, 0, stream>>>(logits);
  k_ctx<<<dim3(8, 64), 256, 0, stream>>>(x, mem, logits, part);
  k_ctxreduce<<<dim3(1024), 256, 0, stream>>>(part, ctx);
  k_ov<<<dim3(16, 4), 256, 0, stream>>>(ctx, Wv, bv, out1);
  k_out<<<dim3(16, 4), 256, 0, stream>>>(out1, Wo, bo, out);
}

// Round 2
// 461.016 us; speedup vs baseline: 1.2709x; 1.2709x over previous
//
#include <hip/hip_runtime.h>
#include <hip/hip_bf16.h>
#include <math.h>

// Problem constants
#define B   64
#define C   1024
#define HH  16
#define DD  64
#define MM  2048
#define LL  2049   // M+1
#define NCH 8
#define CHROWS 257
#define SCALE 0.125f
#define AT_NR 8

// ---------------- generic split-K GEMM: out_partial[kc][64][1024] ----------------
// grid (16, 8): bx -> 64-col tile of W (and A base offset for per-head mode),
// by = kc (128-wide K chunk). A row-major with row stride a_row_stride,
// block-x base offset a_bx_off (0 for plain, 1024 for per-head ctx).
__global__ __launch_bounds__(256) void k_gemm(
    const float* __restrict__ A, int a_row_stride, int a_bx_off,
    const float* __restrict__ W, float* __restrict__ P) {
  __shared__ __attribute__((aligned(16))) float a_s[64 * 132];
  __shared__ __attribute__((aligned(16))) float b_s[128 * 68];
  int t = threadIdx.x;
  int jt = blockIdx.x, kc = blockIdx.y;
  const float* Ab = A + (size_t)jt * a_bx_off;
  int k0 = kc * 128;
  for (int idx = t; idx < 2048; idx += 256) {
    int bb = idx >> 5, f4 = idx & 31;
    float4 v = *(const float4*)&Ab[(size_t)bb * a_row_stride + k0 + 4 * f4];
    *(float4*)&a_s[bb * 132 + 4 * f4] = v;
  }
  for (int idx = t; idx < 2048; idx += 256) {
    int kk = idx >> 4, f4 = idx & 15;
    float4 v = *(const float4*)&W[(size_t)(k0 + kk) * 1024 + jt * 64 + 4 * f4];
    *(float4*)&b_s[kk * 68 + 4 * f4] = v;
  }
  __syncthreads();
  int j0 = (t & 15) * 4, b0 = (t >> 4) * 4;
  float4 acc[4];
#pragma unroll
  for (int i = 0; i < 4; ++i) acc[i] = make_float4(0.f, 0.f, 0.f, 0.f);
  for (int k = 0; k < 128; k += 4) {
    float4 w0 = *(const float4*)&b_s[(k + 0) * 68 + j0];
    float4 w1 = *(const float4*)&b_s[(k + 1) * 68 + j0];
    float4 w2 = *(const float4*)&b_s[(k + 2) * 68 + j0];
    float4 w3 = *(const float4*)&b_s[(k + 3) * 68 + j0];
#pragma unroll
    for (int i = 0; i < 4; ++i) {
      float4 av = *(const float4*)&a_s[(b0 + i) * 132 + k];
      acc[i].x += av.x * w0.x + av.y * w1.x + av.z * w2.x + av.w * w3.x;
      acc[i].y += av.x * w0.y + av.y * w1.y + av.z * w2.y + av.w * w3.y;
      acc[i].z += av.x * w0.z + av.y * w1.z + av.z * w2.z + av.w * w3.z;
      acc[i].w += av.x * w0.w + av.y * w1.w + av.z * w2.w + av.w * w3.w;
    }
  }
  size_t ob = (size_t)kc * 65536 + jt * 64;
#pragma unroll
  for (int i = 0; i < 4; ++i)
    *(float4*)&P[ob + (size_t)(b0 + i) * 1024 + j0] = acc[i];
}

// ---------------- reduce 8 K-chunk partials, add biases ----------------
__global__ __launch_bounds__(256) void k_reduce_qp(
    const float* __restrict__ P, const float* __restrict__ bq,
    const float* __restrict__ u, const float* __restrict__ v,
    float* __restrict__ qu, float* __restrict__ qv) {
  int idx = blockIdx.x * 256 + threadIdx.x;  // 16384 float4s
  int b = idx >> 8, f4 = idx & 255;
  size_t off = (size_t)b * 1024 + 4 * f4;
  float4 s = *(const float4*)&P[off];
#pragma unroll
  for (int kc = 1; kc < 8; ++kc) {
    float4 t4 = *(const float4*)&P[(size_t)kc * 65536 + off];
    s.x += t4.x; s.y += t4.y; s.z += t4.z; s.w += t4.w;
  }
  float4 bb = *(const float4*)&bq[4 * f4];
  s.x += bb.x; s.y += bb.y; s.z += bb.z; s.w += bb.w;
  float4 uu = *(const float4*)&u[4 * f4];
  float4 vv = *(const float4*)&v[4 * f4];
  float4 o1 = make_float4(s.x + uu.x, s.y + uu.y, s.z + uu.z, s.w + uu.w);
  float4 o2 = make_float4(s.x + vv.x, s.y + vv.y, s.z + vv.z, s.w + vv.w);
  *(float4*)&qu[off] = o1;
  *(float4*)&qv[off] = o2;
}

__global__ __launch_bounds__(256) void k_reduce1(
    const float* __restrict__ P, const float* __restrict__ bias,
    float* __restrict__ out) {
  int idx = blockIdx.x * 256 + threadIdx.x;
  int b = idx >> 8, f4 = idx & 255;
  size_t off = (size_t)b * 1024 + 4 * f4;
  float4 s = *(const float4*)&P[off];
#pragma unroll
  for (int kc = 1; kc < 8; ++kc) {
    float4 t4 = *(const float4*)&P[(size_t)kc * 65536 + off];
    s.x += t4.x; s.y += t4.y; s.z += t4.z; s.w += t4.w;
  }
  float4 bb = *(const float4*)&bias[4 * f4];
  s.x += bb.x; s.y += bb.y; s.z += bb.z; s.w += bb.w;
  *(float4*)&out[off] = s;
}

// ---------------- wtilde: per-h GEMM qu_h[64,64] @ Wk_h^T[64,1024] ----------------
// grid (16 c-tiles, 16 h); wt[b,h,c] = sum_d qu[b,h*64+d] * Wk[c, h*64+d]
__global__ __launch_bounds__(256) void k_wtilde(
    const float* __restrict__ qu, const float* __restrict__ Wk,
    float* __restrict__ wt) {
  __shared__ __attribute__((aligned(16))) float a_s[64 * 68];
  __shared__ __attribute__((aligned(16))) float w_s[64 * 68];
  int t = threadIdx.x, ct = blockIdx.x, h = blockIdx.y;
  for (int idx = t; idx < 1024; idx += 256) {
    int bb = idx >> 4, f4 = idx & 15;
    *(float4*)&a_s[bb * 68 + 4 * f4] =
        *(const float4*)&qu[(size_t)bb * 1024 + h * 64 + 4 * f4];
  }
  for (int idx = t; idx < 1024; idx += 256) {
    int cc = idx >> 4, f4 = idx & 15;
    *(float4*)&w_s[cc * 68 + 4 * f4] =
        *(const float4*)&Wk[(size_t)(ct * 64 + cc) * 1024 + h * 64 + 4 * f4];
  }
  __syncthreads();
  int c0 = (t & 15) * 4, b0 = (t >> 4) * 4;
  float acc[4][4] = {};
  for (int d = 0; d < 64; d += 4) {
    float4 w0 = *(const float4*)&w_s[(c0 + 0) * 68 + d];
    float4 w1 = *(const float4*)&w_s[(c0 + 1) * 68 + d];
    float4 w2 = *(const float4*)&w_s[(c0 + 2) * 68 + d];
    float4 w3 = *(const float4*)&w_s[(c0 + 3) * 68 + d];
#pragma unroll
    for (int i = 0; i < 4; ++i) {
      float4 av = *(const float4*)&a_s[(b0 + i) * 68 + d];
      acc[i][0] += av.x * w0.x + av.y * w0.y + av.z * w0.z + av.w * w0.w;
      acc[i][1] += av.x * w1.x + av.y * w1.y + av.z * w1.z + av.w * w1.w;
      acc[i][2] += av.x * w2.x + av.y * w2.y + av.z * w2.z + av.w * w2.w;
      acc[i][3] += av.x * w3.x + av.y * w3.y + av.z * w3.z + av.w * w3.w;
    }
  }
#pragma unroll
  for (int i = 0; i < 4; ++i) {
    float4 o = make_float4(acc[i][0], acc[i][1], acc[i][2], acc[i][3]);
    *(float4*)&wt[(size_t)((b0 + i) * 16 + h) * 1024 + ct * 64 + c0] = o;
  }
}

// ---------------- sinusoidal table, reversed ----------------
__global__ void k_rtab(float* __restrict__ rtab) {
  int idx = blockIdx.x * 256 + threadIdx.x;
  if (idx >= LL * 64) return;
  int l = idx >> 6, d = idx & 63;
  float p = (float)(LL - 1 - l);
  int dd = d & 31;
  float f = 1.0f / powf(10000.0f, (float)dd * (1.0f / 32.0f));
  float a = p * f;
  rtab[idx] = (d < 32) ? sinf(a) : cosf(a);
}

// ---------------- fused flash attention over mem: one pass ----------------
// grid (8 chunks, 64 b), 256 threads. Per block: rows l in [ch*257, ...).
// Produces unnormalized ctx partial + (m, s) per (b, ch, h).
__global__ __launch_bounds__(256, 2) void k_attn(
    const float* __restrict__ x, const float* __restrict__ mem,
    const float* __restrict__ wt, const float* __restrict__ qv,
    const float* __restrict__ rtab, float* __restrict__ part,
    float* __restrict__ ms) {
  __shared__ __attribute__((aligned(16))) float cat_s[AT_NR * 1088];
  __shared__ __attribute__((aligned(16))) float r_s[AT_NR * 68];
  __shared__ float lo_s[16 * AT_NR];
  __shared__ float p_s[AT_NR * 16];
  __shared__ float f_s[16];
  int t = threadIdx.x;
  int lane = t & 63, w = t >> 6;
  int cg = lane >> 2, hl = lane & 3;
  int b = blockIdx.y, ch = blockIdx.x;
  int l0b = ch * CHROWS, lend = min(LL, l0b + CHROWS);
  int h = w * 4 + hl;
  float4 wreg[16];
  const float* wbase = &wt[(size_t)(b * 16 + h) * 1024 + cg * 64];
#pragma unroll
  for (int i = 0; i < 16; ++i) wreg[i] = *(const float4*)&wbase[4 * i];
  float4 qvr = *(const float4*)&qv[(size_t)b * 1024 + h * 64 + 4 * cg];
  float4 ctx[16];
#pragma unroll
  for (int i = 0; i < 16; ++i) ctx[i] = make_float4(0.f, 0.f, 0.f, 0.f);
  float m_h = -3e38f, s_h = 0.f;  // live in threads 0..15 only

  const float* crb = &cat_s[(t >> 4) * 68 + (t & 15) * 4];

  for (int g0 = l0b; g0 < lend; g0 += AT_NR) {
    int nr = min(AT_NR, lend - g0);
    // A: stage cat rows (68-float chunks) + rtab rows
    for (int i = t; i < nr * 256; i += 256) {
      int row = i >> 8, c4 = i & 255;
      int l = g0 + row;
      const float* src = (l < MM) ? &mem[((size_t)b * MM + l) * 1024]
                                  : &x[(size_t)b * 1024];
      float4 v = *(const float4*)&src[4 * c4];
      int chunk = c4 >> 4, off = (c4 & 15) * 4;
      *(float4*)&cat_s[row * 1088 + chunk * 68 + off] = v;
    }
    for (int i = t; i < nr * 16; i += 256) {
      int row = i >> 4, d4 = i & 15;
      *(float4*)&r_s[row * 68 + 4 * d4] =
          *(const float4*)&rtab[(size_t)(g0 + row) * 64 + 4 * d4];
    }
    __syncthreads();
    // B: logits for nr rows x 16 h
    for (int row = 0; row < nr; ++row) {
      const float* cr = &cat_s[row * 1088 + cg * 68];
      float4 rv = *(const float4*)&r_s[row * 68 + 4 * cg];
      float lg = qvr.x * rv.x + qvr.y * rv.y + qvr.z * rv.z + qvr.w * rv.w;
#pragma unroll
      for (int i = 0; i < 16; ++i) {
        float4 cv = *(const float4*)&cr[4 * i];
        lg += cv.x * wreg[i].x + cv.y * wreg[i].y + cv.z * wreg[i].z +
              cv.w * wreg[i].w;
      }
      lg += __shfl_xor(lg, 4, 64);
      lg += __shfl_xor(lg, 8, 64);
      lg += __shfl_xor(lg, 16, 64);
      lg += __shfl_xor(lg, 32, 64);
      if (cg == 0) lo_s[h * AT_NR + row] = lg * SCALE;
    }
    __syncthreads();
    // D: online softmax update (threads 0..15, h = t)
    if (t < 16) {
      float tm = -3e38f;
      for (int r = 0; r < nr; ++r) tm = fmaxf(tm, lo_s[t * AT_NR + r]);
      float mnew = fmaxf(m_h, tm);
      float f = __expf(m_h - mnew);
      float ssum = 0.f;
      for (int r = 0; r < nr; ++r) {
        float e = __expf(lo_s[t * AT_NR + r] - mnew);
        p_s[r * 16 + t] = e;
        ssum += e;
      }
      s_h = s_h * f + ssum;
      m_h = mnew;
      f_s[t] = f;
    }
    __syncthreads();
    // E: rescale + accumulate ctx
#pragma unroll
    for (int hh = 0; hh < 16; ++hh) {
      float f = f_s[hh];
      if (f != 1.0f) {
        ctx[hh].x *= f; ctx[hh].y *= f; ctx[hh].z *= f; ctx[hh].w *= f;
      }
    }
    for (int row = 0; row < nr; ++row) {
      float4 cv = *(const float4*)&crb[row * 1088];
      const float* pr = &p_s[row * 16];
      float4 pA = *(const float4*)&pr[0];
      float4 pB = *(const float4*)&pr[4];
      float4 pC = *(const float4*)&pr[8];
      float4 pD = *(const float4*)&pr[12];
#define ACC1(idx, pv)                                                   \
  ctx[idx].x += (pv) * cv.x; ctx[idx].y += (pv) * cv.y;                 \
  ctx[idx].z += (pv) * cv.z; ctx[idx].w += (pv) * cv.w;
      ACC1(0, pA.x) ACC1(1, pA.y) ACC1(2, pA.z) ACC1(3, pA.w)
      ACC1(4, pB.x) ACC1(5, pB.y) ACC1(6, pB.z) ACC1(7, pB.w)
      ACC1(8, pC.x) ACC1(9, pC.y) ACC1(10, pC.z) ACC1(11, pC.w)
      ACC1(12, pD.x) ACC1(13, pD.y) ACC1(14, pD.z) ACC1(15, pD.w)
#undef ACC1
    }
    __syncthreads();
  }
  // write partials
  size_t pb = ((size_t)(b * 8 + ch) * 16) * 1024;
#pragma unroll
  for (int hh = 0; hh < 16; ++hh)
    *(float4*)&part[pb + (size_t)hh * 1024 + 4 * t] = ctx[hh];
  if (t < 16) {
    ms[((size_t)(b * 8 + ch) * 16 + t) * 2 + 0] = m_h;
    ms[((size_t)(b * 8 + ch) * 16 + t) * 2 + 1] = s_h;
  }
}

// ---------------- combine chunk partials -> normalized ctx ----------------
// grid (4 c-quarters, 64 b), 256 threads
__global__ __launch_bounds__(256) void k_combine(
    const float* __restrict__ part, const float* __restrict__ ms,
    float* __restrict__ ctx) {
  __shared__ float ms_s[256];
  __shared__ float wsc[128];
  int t = threadIdx.x, cq = blockIdx.x, b = blockIdx.y;
  ms_s[t] = ms[(size_t)b * 256 + t];
  __syncthreads();
  if (t < 16) {
    float M = -3e38f;
#pragma unroll
    for (int ch = 0; ch < 8; ++ch) M = fmaxf(M, ms_s[ch * 32 + t * 2]);
    float den = 0.f;
#pragma unroll
    for (int ch = 0; ch < 8; ++ch)
      den += __expf(ms_s[ch * 32 + t * 2] - M) * ms_s[ch * 32 + t * 2 + 1];
    float inv = 1.0f / den;
#pragma unroll
    for (int ch = 0; ch < 8; ++ch)
      wsc[ch * 16 + t] = __expf(ms_s[ch * 32 + t * 2] - M) * inv;
  }
  __syncthreads();
  int c = cq * 256 + t;
  for (int h = 0; h < 16; ++h) {
    float acc = 0.f;
#pragma unroll
    for (int ch = 0; ch < 8; ++ch)
      acc += wsc[ch * 16 + h] * part[(size_t)((b * 8 + ch) * 16 + h) * 1024 + c];
    ctx[(size_t)(b * 16 + h) * 1024 + c] = acc;
  }
}

extern "C" void kernel_launch(void* const* d_in, const int* in_sizes, int n_in,
                              void* d_out, int out_size, void* d_ws,
                              size_t ws_size, hipStream_t stream) {
  const float* x = (const float*)d_in[0];
  const float* mem = (const float*)d_in[1];
  const float* Wq = (const float*)d_in[2];
  const float* bq = (const float*)d_in[3];
  const float* Wk = (const float*)d_in[4];
  // d_in[5] = bk : constant over l -> cancels in softmax, unused.
  const float* Wv = (const float*)d_in[6];
  const float* bv = (const float*)d_in[7];
  const float* u_bias = (const float*)d_in[8];
  const float* v_bias = (const float*)d_in[9];
  const float* Wo = (const float*)d_in[10];
  const float* bo = (const float*)d_in[11];
  float* out = (float*)d_out;

  float* ws = (float*)d_ws;
  float* qu = ws;                         // 65536
  float* qv = qu + 65536;                 // 65536
  float* wt = qv + 65536;                 // 1048576
  float* rtab = wt + 1048576;             // 131200
  float* part = rtab + 131200;            // 8388608
  float* ms = part + 8388608;             // 16384
  float* P = ms + 16384;                  // 524288
  float* ctx = P + 524288;                // 1048576
  float* out1 = ctx + 1048576;            // 65536
  // total ~11.35M floats = 45.4 MB

  k_gemm<<<dim3(16, 8), 256, 0, stream>>>(x, 1024, 0, Wq, P);
  k_rtab<<<dim3(513), 256, 0, stream>>>(rtab);
  k_reduce_qp<<<dim3(64), 256, 0, stream>>>(P, bq, u_bias, v_bias, qu, qv);
  k_wtilde<<<dim3(16, 16), 256, 0, stream>>>(qu, Wk, wt);
  k_attn<<<dim3(8, 64), 256, 0, stream>>>(x, mem, wt, qv, rtab, part, ms);
  k_combine<<<dim3(4, 64), 256, 0, stream>>>(part, ms, ctx);
  k_gemm<<<dim3(16, 8), 256, 0, stream>>>(ctx, 16384, 1024, Wv, P);
  k_reduce1<<<dim3(64), 256, 0, stream>>>(P, bv, out1);
  k_gemm<<<dim3(16, 8), 256, 0, stream>>>(out1, 1024, 0, Wo, P);
  k_reduce1<<<dim3(64), 256, 0, stream>>>(P, bo, out);
}

// Round 3
// 431.212 us; speedup vs baseline: 1.3587x; 1.0691x over previous
//
#include <hip/hip_runtime.h>
#include <hip/hip_bf16.h>
#include <math.h>

// Problem constants
#define B   64
#define C   1024
#define HH  16
#define DD  64
#define MM  2048
#define LL  2049   // M+1
#define SCALE 0.125f
#define NCHC 9     // ctx row chunks
#define CHC  228   // rows per ctx chunk (9*228 = 2052 >= 2049)

// ---------------- generic split-K GEMM: out_partial[kc][64][1024] ----------------
__global__ __launch_bounds__(256) void k_gemm(
    const float* __restrict__ A, int a_row_stride, int a_bx_off,
    const float* __restrict__ W, float* __restrict__ P) {
  __shared__ __attribute__((aligned(16))) float a_s[64 * 132];
  __shared__ __attribute__((aligned(16))) float b_s[128 * 68];
  int t = threadIdx.x;
  int jt = blockIdx.x, kc = blockIdx.y;
  const float* Ab = A + (size_t)jt * a_bx_off;
  int k0 = kc * 128;
  for (int idx = t; idx < 2048; idx += 256) {
    int bb = idx >> 5, f4 = idx & 31;
    float4 v = *(const float4*)&Ab[(size_t)bb * a_row_stride + k0 + 4 * f4];
    *(float4*)&a_s[bb * 132 + 4 * f4] = v;
  }
  for (int idx = t; idx < 2048; idx += 256) {
    int kk = idx >> 4, f4 = idx & 15;
    float4 v = *(const float4*)&W[(size_t)(k0 + kk) * 1024 + jt * 64 + 4 * f4];
    *(float4*)&b_s[kk * 68 + 4 * f4] = v;
  }
  __syncthreads();
  int j0 = (t & 15) * 4, b0 = (t >> 4) * 4;
  float4 acc[4];
#pragma unroll
  for (int i = 0; i < 4; ++i) acc[i] = make_float4(0.f, 0.f, 0.f, 0.f);
  for (int k = 0; k < 128; k += 4) {
    float4 w0 = *(const float4*)&b_s[(k + 0) * 68 + j0];
    float4 w1 = *(const float4*)&b_s[(k + 1) * 68 + j0];
    float4 w2 = *(const float4*)&b_s[(k + 2) * 68 + j0];
    float4 w3 = *(const float4*)&b_s[(k + 3) * 68 + j0];
#pragma unroll
    for (int i = 0; i < 4; ++i) {
      float4 av = *(const float4*)&a_s[(b0 + i) * 132 + k];
      acc[i].x += av.x * w0.x + av.y * w1.x + av.z * w2.x + av.w * w3.x;
      acc[i].y += av.x * w0.y + av.y * w1.y + av.z * w2.y + av.w * w3.y;
      acc[i].z += av.x * w0.z + av.y * w1.z + av.z * w2.z + av.w * w3.z;
      acc[i].w += av.x * w0.w + av.y * w1.w + av.z * w2.w + av.w * w3.w;
    }
  }
  size_t ob = (size_t)kc * 65536 + jt * 64;
#pragma unroll
  for (int i = 0; i < 4; ++i)
    *(float4*)&P[ob + (size_t)(b0 + i) * 1024 + j0] = acc[i];
}

__global__ __launch_bounds__(256) void k_reduce_qp(
    const float* __restrict__ P, const float* __restrict__ bq,
    const float* __restrict__ u, const float* __restrict__ v,
    float* __restrict__ qu, float* __restrict__ qv) {
  int idx = blockIdx.x * 256 + threadIdx.x;
  int b = idx >> 8, f4 = idx & 255;
  size_t off = (size_t)b * 1024 + 4 * f4;
  float4 s = *(const float4*)&P[off];
#pragma unroll
  for (int kc = 1; kc < 8; ++kc) {
    float4 t4 = *(const float4*)&P[(size_t)kc * 65536 + off];
    s.x += t4.x; s.y += t4.y; s.z += t4.z; s.w += t4.w;
  }
  float4 bb = *(const float4*)&bq[4 * f4];
  s.x += bb.x; s.y += bb.y; s.z += bb.z; s.w += bb.w;
  float4 uu = *(const float4*)&u[4 * f4];
  float4 vv = *(const float4*)&v[4 * f4];
  float4 o1 = make_float4(s.x + uu.x, s.y + uu.y, s.z + uu.z, s.w + uu.w);
  float4 o2 = make_float4(s.x + vv.x, s.y + vv.y, s.z + vv.z, s.w + vv.w);
  *(float4*)&qu[off] = o1;
  *(float4*)&qv[off] = o2;
}

__global__ __launch_bounds__(256) void k_reduce1(
    const float* __restrict__ P, const float* __restrict__ bias,
    float* __restrict__ out) {
  int idx = blockIdx.x * 256 + threadIdx.x;
  int b = idx >> 8, f4 = idx & 255;
  size_t off = (size_t)b * 1024 + 4 * f4;
  float4 s = *(const float4*)&P[off];
#pragma unroll
  for (int kc = 1; kc < 8; ++kc) {
    float4 t4 = *(const float4*)&P[(size_t)kc * 65536 + off];
    s.x += t4.x; s.y += t4.y; s.z += t4.z; s.w += t4.w;
  }
  float4 bb = *(const float4*)&bias[4 * f4];
  s.x += bb.x; s.y += bb.y; s.z += bb.z; s.w += bb.w;
  *(float4*)&out[off] = s;
}

// ---------------- wtilde: per-h GEMM ----------------
__global__ __launch_bounds__(256) void k_wtilde(
    const float* __restrict__ qu, const float* __restrict__ Wk,
    float* __restrict__ wt) {
  __shared__ __attribute__((aligned(16))) float a_s[64 * 68];
  __shared__ __attribute__((aligned(16))) float w_s[64 * 68];
  int t = threadIdx.x, ct = blockIdx.x, h = blockIdx.y;
  for (int idx = t; idx < 1024; idx += 256) {
    int bb = idx >> 4, f4 = idx & 15;
    *(float4*)&a_s[bb * 68 + 4 * f4] =
        *(const float4*)&qu[(size_t)bb * 1024 + h * 64 + 4 * f4];
  }
  for (int idx = t; idx < 1024; idx += 256) {
    int cc = idx >> 4, f4 = idx & 15;
    *(float4*)&w_s[cc * 68 + 4 * f4] =
        *(const float4*)&Wk[(size_t)(ct * 64 + cc) * 1024 + h * 64 + 4 * f4];
  }
  __syncthreads();
  int c0 = (t & 15) * 4, b0 = (t >> 4) * 4;
  float acc[4][4] = {};
  for (int d = 0; d < 64; d += 4) {
    float4 w0 = *(const float4*)&w_s[(c0 + 0) * 68 + d];
    float4 w1 = *(const float4*)&w_s[(c0 + 1) * 68 + d];
    float4 w2 = *(const float4*)&w_s[(c0 + 2) * 68 + d];
    float4 w3 = *(const float4*)&w_s[(c0 + 3) * 68 + d];
#pragma unroll
    for (int i = 0; i < 4; ++i) {
      float4 av = *(const float4*)&a_s[(b0 + i) * 68 + d];
      acc[i][0] += av.x * w0.x + av.y * w0.y + av.z * w0.z + av.w * w0.w;
      acc[i][1] += av.x * w1.x + av.y * w1.y + av.z * w1.z + av.w * w1.w;
      acc[i][2] += av.x * w2.x + av.y * w2.y + av.z * w2.z + av.w * w2.w;
      acc[i][3] += av.x * w3.x + av.y * w3.y + av.z * w3.z + av.w * w3.w;
    }
  }
#pragma unroll
  for (int i = 0; i < 4; ++i) {
    float4 o = make_float4(acc[i][0], acc[i][1], acc[i][2], acc[i][3]);
    *(float4*)&wt[(size_t)((b0 + i) * 16 + h) * 1024 + ct * 64 + c0] = o;
  }
}

// ---------------- sinusoidal table, reversed ----------------
__global__ void k_rtab(float* __restrict__ rtab) {
  int idx = blockIdx.x * 256 + threadIdx.x;
  if (idx >= LL * 64) return;
  int l = idx >> 6, d = idx & 63;
  float p = (float)(LL - 1 - l);
  int dd = d & 31;
  float f = 1.0f / powf(10000.0f, (float)dd * (1.0f / 32.0f));
  float a = p * f;
  rtab[idx] = (d < 32) ? sinf(a) : cosf(a);
}

// ---------------- bd[b,h,l] = sum_d qv[b,h,d]*rtab[l,d] ----------------
// grid (17, 64): 128 l-rows per block
__global__ __launch_bounds__(256) void k_bd(
    const float* __restrict__ qv, const float* __restrict__ rtab,
    float* __restrict__ bd) {
  __shared__ __attribute__((aligned(16))) float rt_s[128 * 68];
  int t = threadIdx.x, ch = blockIdx.x, b = blockIdx.y;
  int l0 = ch * 128;
  int nrows = min(128, LL - l0);
  for (int idx = t; idx < nrows * 16; idx += 256) {
    int r = idx >> 4, d4 = idx & 15;
    *(float4*)&rt_s[r * 68 + 4 * d4] =
        *(const float4*)&rtab[(size_t)(l0 + r) * 64 + 4 * d4];
  }
  __syncthreads();
  for (int idx = t; idx < 16 * 128; idx += 256) {
    int h = idx >> 7, r = idx & 127;
    if (r < nrows) {
      const float* qh = &qv[(size_t)b * 1024 + h * 64];
      const float* rr = &rt_s[r * 68];
      float s = 0.f;
#pragma unroll
      for (int d4 = 0; d4 < 16; ++d4) {
        float4 rv = *(const float4*)&rr[4 * d4];
        float4 qq = *(const float4*)&qh[4 * d4];
        s += rv.x * qq.x + rv.y * qq.y + rv.z * qq.z + rv.w * qq.w;
      }
      bd[(size_t)(b * 16 + h) * LL + l0 + r] = s;
    }
  }
}

// ---------------- logits pass: register-resident, global-direct ----------------
// grid (17, 64): 128 rows per block; 4 waves c-split (256 c each);
// lane owns 4 c with wt for all 16 h in registers; packed butterfly reduce.
__global__ __launch_bounds__(256) void k_logits(
    const float* __restrict__ x, const float* __restrict__ mem,
    const float* __restrict__ wt, const float* __restrict__ bd,
    float* __restrict__ logits) {
  __shared__ float red_s[8 * 68];
  int t = threadIdx.x;
  int lane = t & 63, w = t >> 6;
  int b = blockIdx.y, ch = blockIdx.x;
  int l0 = ch * 128, lend = min(LL, l0 + 128);
  int c_off = w * 256 + lane * 4;
  float4 wr[16];
#pragma unroll
  for (int h = 0; h < 16; ++h)
    wr[h] = *(const float4*)&wt[(size_t)(b * 16 + h) * 1024 + c_off];
  const float* xrow = &x[(size_t)b * 1024 + c_off];
  const float* memb = &mem[(size_t)b * MM * 1024 + c_off];
  bool b5 = (lane & 32) != 0, b4 = (lane & 16) != 0;
  bool b3 = (lane & 8) != 0, b2 = (lane & 4) != 0;
  int hl = lane >> 2;  // h this lane holds after the packed reduce

  for (int g0 = l0; g0 < lend; g0 += 8) {
    int nr = min(8, lend - g0);
    float4 rb[8];
#pragma unroll
    for (int r = 0; r < 8; ++r) {
      int l = g0 + r;
      rb[r] = *(const float4*)((l < MM) ? &memb[(size_t)l * 1024] : xrow);
    }
#pragma unroll
    for (int r = 0; r < 8; ++r) {
      if (r < nr) {
        float4 rv = rb[r];
        float p[16];
#pragma unroll
        for (int h = 0; h < 16; ++h)
          p[h] = rv.x * wr[h].x + rv.y * wr[h].y + rv.z * wr[h].z +
                 rv.w * wr[h].w;
        // packed butterfly: 16 vals/lane over 64 lanes -> 1 val/lane
        float q[8];
#pragma unroll
        for (int i = 0; i < 8; ++i) {
          float send = b5 ? p[i] : p[i + 8];
          float keep = b5 ? p[i + 8] : p[i];
          q[i] = keep + __shfl_xor(send, 32, 64);
        }
        float r2[4];
#pragma unroll
        for (int i = 0; i < 4; ++i) {
          float send = b4 ? q[i] : q[i + 4];
          float keep = b4 ? q[i + 4] : q[i];
          r2[i] = keep + __shfl_xor(send, 16, 64);
        }
        float s2[2];
#pragma unroll
        for (int i = 0; i < 2; ++i) {
          float send = b3 ? r2[i] : r2[i + 2];
          float keep = b3 ? r2[i + 2] : r2[i];
          s2[i] = keep + __shfl_xor(send, 8, 64);
        }
        float send4 = b2 ? s2[0] : s2[1];
        float keep4 = b2 ? s2[1] : s2[0];
        float u = keep4 + __shfl_xor(send4, 4, 64);
        u += __shfl_xor(u, 1, 64);
        u += __shfl_xor(u, 2, 64);
        if ((lane & 3) == 0) red_s[r * 68 + w * 16 + hl] = u;
      }
    }
    __syncthreads();
    if (t < 128) {
      int r8 = t & 7, h = t >> 3;
      if (r8 < nr) {
        float s = red_s[r8 * 68 + h] + red_s[r8 * 68 + 16 + h] +
                  red_s[r8 * 68 + 32 + h] + red_s[r8 * 68 + 48 + h];
        int l = g0 + r8;
        size_t o = (size_t)(b * 16 + h) * LL + l;
        logits[o] = (s + bd[o]) * SCALE;
      }
    }
    __syncthreads();
  }
}

// ---------------- softmax over l, in place. grid 1024 (b*16+h) ----------------
__global__ __launch_bounds__(256) void k_softmax(float* __restrict__ logits) {
  __shared__ float red[8];
  int t = threadIdx.x;
  size_t base = (size_t)blockIdx.x * LL;
  float rv[9];
  float m = -1e30f;
#pragma unroll
  for (int k = 0; k < 9; ++k) {
    int i = t + k * 256;
    rv[k] = (i < LL) ? logits[base + i] : -1e30f;
    m = fmaxf(m, rv[k]);
  }
#pragma unroll
  for (int s = 1; s < 64; s <<= 1) m = fmaxf(m, __shfl_xor(m, s, 64));
  if ((t & 63) == 0) red[t >> 6] = m;
  __syncthreads();
  m = fmaxf(fmaxf(red[0], red[1]), fmaxf(red[2], red[3]));
  float sum = 0.f;
#pragma unroll
  for (int k = 0; k < 9; ++k) {
    int i = t + k * 256;
    float e = __expf(rv[k] - m);
    rv[k] = e;
    if (i < LL) sum += e;
  }
#pragma unroll
  for (int s = 1; s < 64; s <<= 1) sum += __shfl_xor(sum, s, 64);
  if ((t & 63) == 0) red[4 + (t >> 6)] = sum;
  __syncthreads();
  float inv = 1.0f / (red[4] + red[5] + red[6] + red[7]);
#pragma unroll
  for (int k = 0; k < 9; ++k) {
    int i = t + k * 256;
    if (i < LL) logits[base + i] = rv[k] * inv;
  }
}

// ---------------- ctx pass: register-resident, global-direct ----------------
// grid (36, 64): bx = ch*4 + cq. Block: rows [ch*228, +228), c-quarter cq.
// 4 waves split rows (8-row groups, stride 32); lane owns 4 c, acc[16h].
__global__ __launch_bounds__(256) void k_ctx(
    const float* __restrict__ x, const float* __restrict__ mem,
    const float* __restrict__ attn, float* __restrict__ part) {
  __shared__ __attribute__((aligned(16))) float att_s[CHC * 20];
  int t = threadIdx.x;
  int lane = t & 63, w = t >> 6;
  int b = blockIdx.y;
  int ch = blockIdx.x >> 2, cq = blockIdx.x & 3;
  int l0 = ch * CHC, lend = min(LL, l0 + CHC);
  int natt = lend - l0;
  int c_off = cq * 256 + lane * 4;
#pragma unroll
  for (int h = 0; h < 16; ++h)
    for (int r = t; r < natt; r += 256)
      att_s[r * 20 + h] = attn[(size_t)(b * 16 + h) * LL + l0 + r];
  __syncthreads();
  float4 acc[16];
#pragma unroll
  for (int i = 0; i < 16; ++i) acc[i] = make_float4(0.f, 0.f, 0.f, 0.f);
  const float* xrow = &x[(size_t)b * 1024 + c_off];
  const float* memb = &mem[(size_t)b * MM * 1024 + c_off];

  for (int g0 = l0 + w * 8; g0 < lend; g0 += 32) {
    int nr = min(8, lend - g0);
    float4 rb[8];
#pragma unroll
    for (int r = 0; r < 8; ++r) {
      int l = g0 + r;
      rb[r] = *(const float4*)((l < MM) ? &memb[(size_t)l * 1024] : xrow);
    }
#pragma unroll
    for (int r = 0; r < 8; ++r) {
      if (r < nr) {
        int ri = g0 + r - l0;
        const float4* a4 = (const float4*)&att_s[ri * 20];
        float4 aA = a4[0], aB = a4[1], aC = a4[2], aD = a4[3];
        float4 rv = rb[r];
#define ACC1(i, s)                                                       \
  acc[i].x += (s) * rv.x; acc[i].y += (s) * rv.y;                        \
  acc[i].z += (s) * rv.z; acc[i].w += (s) * rv.w;
        ACC1(0, aA.x) ACC1(1, aA.y) ACC1(2, aA.z) ACC1(3, aA.w)
        ACC1(4, aB.x) ACC1(5, aB.y) ACC1(6, aB.z) ACC1(7, aB.w)
        ACC1(8, aC.x) ACC1(9, aC.y) ACC1(10, aC.z) ACC1(11, aC.w)
        ACC1(12, aD.x) ACC1(13, aD.y) ACC1(14, aD.z) ACC1(15, aD.w)
#undef ACC1
      }
    }
  }
  // cross-wave merge in LDS (reuse att_s: 4096 <= 4560 floats)
  __syncthreads();
  float* accb = att_s;
  for (int ww = 0; ww < 4; ++ww) {
    if (w == ww) {
      if (ww == 0) {
#pragma unroll
        for (int h = 0; h < 16; ++h)
          *(float4*)&accb[h * 256 + lane * 4] = acc[h];
      } else {
#pragma unroll
        for (int h = 0; h < 16; ++h) {
          float4 vv = *(const float4*)&accb[h * 256 + lane * 4];
          vv.x += acc[h].x; vv.y += acc[h].y;
          vv.z += acc[h].z; vv.w += acc[h].w;
          *(float4*)&accb[h * 256 + lane * 4] = vv;
        }
      }
    }
    __syncthreads();
  }
  size_t pb = (size_t)((b * NCHC + ch) * 16) * 1024 + cq * 256;
  for (int idx = t; idx < 1024; idx += 256) {
    int h = idx >> 6, c4 = idx & 63;
    *(float4*)&part[pb + (size_t)h * 1024 + 4 * c4] =
        *(const float4*)&accb[h * 256 + 4 * c4];
  }
}

// ---------------- sum 9 chunk partials -> ctx ----------------
__global__ __launch_bounds__(256) void k_ctxreduce(
    const float* __restrict__ part, float* __restrict__ ctx) {
  int o4 = blockIdx.x * 256 + threadIdx.x;  // 262144 float4s
  size_t o = (size_t)o4 * 4;
  int b = (int)(o >> 14);
  int rem = (int)(o & 16383);
  const float* p = &part[(size_t)b * (NCHC * 16384) + rem];
  float4 s = *(const float4*)p;
#pragma unroll
  for (int chk = 1; chk < NCHC; ++chk) {
    float4 v = *(const float4*)&p[(size_t)chk * 16384];
    s.x += v.x; s.y += v.y; s.z += v.z; s.w += v.w;
  }
  *(float4*)&ctx[o] = s;
}

extern "C" void kernel_launch(void* const* d_in, const int* in_sizes, int n_in,
                              void* d_out, int out_size, void* d_ws,
                              size_t ws_size, hipStream_t stream) {
  const float* x = (const float*)d_in[0];
  const float* mem = (const float*)d_in[1];
  const float* Wq = (const float*)d_in[2];
  const float* bq = (const float*)d_in[3];
  const float* Wk = (const float*)d_in[4];
  // d_in[5] = bk : constant over l -> cancels in softmax, unused.
  const float* Wv = (const float*)d_in[6];
  const float* bv = (const float*)d_in[7];
  const float* u_bias = (const float*)d_in[8];
  const float* v_bias = (const float*)d_in[9];
  const float* Wo = (const float*)d_in[10];
  const float* bo = (const float*)d_in[11];
  float* out = (float*)d_out;

  float* ws = (float*)d_ws;
  // Region A (persistent): 3,343,360 floats
  float* qu = ws;                         // 65536
  float* qv = qu + 65536;                 // 65536
  float* logits = qv + 65536;             // 2098176
  float* ctx = logits + 2098176;          // 1048576
  float* out1 = ctx + 1048576;            // 65536
  // Region B (aliased): 9,437,184 floats (= part)
  float* Bb = out1 + 65536;
  float* wt = Bb;                         // 1048576 (dead after k_logits)
  float* rtab = Bb + 1048576;             // 131200  (dead after k_bd)
  float* bd = Bb + 1179776;               // 2098176 (dead after k_logits)
  float* P = Bb + 3277952;                // 524288  (early use + post-part use)
  float* part = Bb;                       // 9437184 (k_ctx..k_ctxreduce only)
  // total = 12,780,544 floats = 51.1 MB

  k_gemm<<<dim3(16, 8), 256, 0, stream>>>(x, 1024, 0, Wq, P);
  k_rtab<<<dim3(513), 256, 0, stream>>>(rtab);
  k_reduce_qp<<<dim3(64), 256, 0, stream>>>(P, bq, u_bias, v_bias, qu, qv);
  k_wtilde<<<dim3(16, 16), 256, 0, stream>>>(qu, Wk, wt);
  k_bd<<<dim3(17, 64), 256, 0, stream>>>(qv, rtab, bd);
  k_logits<<<dim3(17, 64), 256, 0, stream>>>(x, mem, wt, bd, logits);
  k_softmax<<<dim3(1024), 256, 0, stream>>>(logits);
  k_ctx<<<dim3(36, 64), 256, 0, stream>>>(x, mem, logits, part);
  k_ctxreduce<<<dim3(1024), 256, 0, stream>>>(part, ctx);
  k_gemm<<<dim3(16, 8), 256, 0, stream>>>(ctx, 16384, 1024, Wv, P);
  k_reduce1<<<dim3(64), 256, 0, stream>>>(P, bv, out1);
  k_gemm<<<dim3(16, 8), 256, 0, stream>>>(out1, 1024, 0, Wo, P);
  k_reduce1<<<dim3(64), 256, 0, stream>>>(P, bo, out);
}